// Round 1
// baseline (319.380 us; speedup 1.0000x reference)
//
#include <hip/hip_runtime.h>
#include <hip/hip_bf16.h>
#include <math.h>

typedef unsigned long long ull;

#define MAXO 24
#define KC_CAP 1024

__device__ __forceinline__ unsigned int xform(float x){
  unsigned int b = __float_as_uint(x);
  return (b & 0x80000000u) ? ~b : (b | 0x80000000u);
}
__device__ __forceinline__ float softplus_(float d){
  return (d > 20.f) ? d : log1pf(expf(d));
}

// ---------------- Kernel A: IoU, per-gt argmax, per-anchor neg mask ----------------
__global__ __launch_bounds__(256) void kA(const float4* __restrict__ anchors,
        const float* __restrict__ targets,
        ull* __restrict__ matchbest, ull* __restrict__ negmask,
        int A, int O){
  int b = blockIdx.y;
  int t = threadIdx.x;
  int lane = t & 63, wid = t >> 6;
  __shared__ float sgt[MAXO*5];
  __shared__ float sarea[MAXO];
  __shared__ ull wk[4][MAXO];
  int n5 = O*5;
  if (t < n5) sgt[t] = targets[b*n5 + t];
  __syncthreads();
  if (t < O){
    float x1=sgt[t*5], y1=sgt[t*5+1], x2=sgt[t*5+2], y2=sgt[t*5+3];
    sarea[t] = __fmul_rn(__fsub_rn(x2,x1), __fsub_rn(y2,y1));
  }
  __syncthreads();

  ull key[MAXO];
  #pragma unroll
  for (int o=0;o<MAXO;o++) key[o]=0;

  int base = blockIdx.x * 1024;
  for (int k=0;k<4;k++){
    int a = base + k*256 + t;
    float4 an = anchors[a];
    float hw = __fmul_rn(an.z, 0.5f), hh = __fmul_rn(an.w, 0.5f);
    float ax1 = __fsub_rn(an.x, hw), ay1 = __fsub_rn(an.y, hh);
    float ax2 = __fadd_rn(an.x, hw), ay2 = __fadd_rn(an.y, hh);
    float aarea = __fmul_rn(__fsub_rn(ax2,ax1), __fsub_rn(ay2,ay1));
    float amax = 0.f;
    for (int o=0;o<O;o++){
      float ltx = fmaxf(sgt[o*5+0], ax1), lty = fmaxf(sgt[o*5+1], ay1);
      float rbx = fminf(sgt[o*5+2], ax2), rby = fminf(sgt[o*5+3], ay2);
      float wx = fmaxf(__fsub_rn(rbx,ltx), 0.f);
      float wy = fmaxf(__fsub_rn(rby,lty), 0.f);
      float inter = __fmul_rn(wx, wy);
      float denom = __fsub_rn(__fadd_rn(sarea[o], aarea), inter);
      float iou = __fdiv_rn(inter, denom);
      amax = fmaxf(amax, iou);
      ull kk = ((ull)__float_as_uint(iou) << 32) | (unsigned int)(~(unsigned int)a);
      if (kk > key[o]) key[o] = kk;
    }
    ull m = __ballot(amax < 0.4f);
    if (lane == 0) negmask[(size_t)b*(A>>6) + (a>>6)] = m;
  }

  // wave reduce each gt's key, then cross-wave, then global atomicMax
  for (int o=0;o<O;o++){
    ull k = key[o];
    #pragma unroll
    for (int s=32; s>=1; s>>=1){
      unsigned int lo = __shfl_down((unsigned int)(k & 0xFFFFFFFFu), s);
      unsigned int hi = __shfl_down((unsigned int)(k >> 32), s);
      ull other = ((ull)hi<<32) | lo;
      if (other > k) k = other;
    }
    if (lane == 0) wk[wid][o] = k;
  }
  __syncthreads();
  if (t < O){
    ull k = wk[0][t];
    for (int w=1; w<4; w++){ ull v = wk[w][t]; if (v>k) k=v; }
    atomicMax(&matchbest[b*O + t], k);
  }
}

// ---------------- Kernel B: positive loc loss + positive CE ----------------
__global__ void kB(const float* __restrict__ loc, const float2* __restrict__ conf,
       const float* __restrict__ targets, const ull* __restrict__ matchbest,
       float* __restrict__ out, int A, int O, int BO, float lscale, float cscale){
  int i = blockIdx.x*blockDim.x + threadIdx.x;
  if (i >= BO) return;
  int b = i / O;
  ull key = matchbest[i];
  unsigned int idx = ~(unsigned int)(key & 0xFFFFFFFFu);
  const float* tg = targets + (size_t)i*5;
  const float* lp = loc + ((size_t)b*A + idx)*4;
  float ll = 0.f;
  #pragma unroll
  for (int d=0; d<4; d++){
    float df = lp[d] - tg[d];
    float ad = fabsf(df);
    ll += (ad < 1.f) ? 0.5f*df*df : (ad - 0.5f);
  }
  float2 c = conf[(size_t)b*A + idx];
  float m = fmaxf(c.x, c.y);
  float lse = m + logf(expf(c.x - m) + expf(c.y - m));
  float ce = lse - c.y;   // label = 1
  atomicAdd(&out[0], ll * lscale);
  atomicAdd(&out[1], ce * cscale);
}

// ---------------- Kernel C: top-K hard negative mining + neg CE ----------------
__global__ __launch_bounds__(1024) void kC(const float2* __restrict__ conf,
        const ull* __restrict__ negmask, float* __restrict__ out,
        int A, int K, float cscale){
  int b = blockIdx.x, t = threadIdx.x;
  int lane = t & 63, wid = t >> 6;
  __shared__ ull smask[1024];
  __shared__ unsigned int h[2048], htmp[2048];
  __shared__ unsigned int cu[KC_CAP], ci[KC_CAP];
  __shared__ unsigned int s_cnt, s_b1, s_S1, s_b2, s_S2;
  __shared__ float wsum[16];
  int nw = A >> 6;
  for (int i=t; i<nw; i+=1024) smask[i] = negmask[(size_t)b*nw + i];
  for (int i=t; i<2048; i+=1024){ h[i]=0; htmp[i]=0; }
  if (t==0){ s_cnt=0; s_b1=0; s_S1=0; s_b2=0; s_S2=0; }
  __syncthreads();
  const float2* cb = conf + (size_t)b*A;
  int iters = A >> 10;

  // pass 1: coarse histogram (top 11 bits)
  for (int j=0;j<iters;j++){
    int a = (j<<10) + t;
    ull w = smask[a>>6];
    if ((w >> (a&63)) & 1ull){
      unsigned int u = xform(cb[a].x);
      atomicAdd(&h[u>>21], 1u);
    }
  }
  __syncthreads();
  {
    unsigned int* src=h; unsigned int* dst=htmp;
    for (int d=1; d<2048; d<<=1){
      for (int i=t;i<2048;i+=1024){
        unsigned int v = src[i]; if (i+d < 2048) v += src[i+d];
        dst[i] = v;
      }
      __syncthreads();
      unsigned int* tmp=src; src=dst; dst=tmp;
    }
    for (int i=t;i<2048;i+=1024){
      unsigned int si = src[i];
      unsigned int sn = (i<2047)? src[i+1] : 0u;
      if (si >= (unsigned int)K && sn < (unsigned int)K){ s_b1 = (unsigned int)i; s_S1 = sn; }
    }
  }
  __syncthreads();
  unsigned int b1 = s_b1;
  unsigned int R = (unsigned int)K - s_S1;
  for (int i=t;i<2048;i+=1024){ h[i]=0; htmp[i]=0; }
  __syncthreads();

  // pass 2: refine within bin b1 (next 11 bits)
  for (int j=0;j<iters;j++){
    int a = (j<<10) + t;
    ull w = smask[a>>6];
    if ((w >> (a&63)) & 1ull){
      unsigned int u = xform(cb[a].x);
      if ((u>>21) == b1) atomicAdd(&h[(u>>10)&2047u], 1u);
    }
  }
  __syncthreads();
  {
    unsigned int* src=h; unsigned int* dst=htmp;
    for (int d=1; d<2048; d<<=1){
      for (int i=t;i<2048;i+=1024){
        unsigned int v = src[i]; if (i+d < 2048) v += src[i+d];
        dst[i] = v;
      }
      __syncthreads();
      unsigned int* tmp=src; src=dst; dst=tmp;
    }
    for (int i=t;i<2048;i+=1024){
      unsigned int si = src[i];
      unsigned int sn = (i<2047)? src[i+1] : 0u;
      if (si >= R && sn < R){ s_b2 = (unsigned int)i; s_S2 = sn; }
    }
  }
  __syncthreads();
  unsigned int key22 = (b1 << 11) | s_b2;
  unsigned int R2 = R - s_S2;

  // pass 3: accumulate CE of definite winners; collect boundary bucket
  float ce = 0.f;
  for (int j=0;j<iters;j++){
    int a = (j<<10) + t;
    ull w = smask[a>>6];
    if ((w >> (a&63)) & 1ull){
      float2 c = cb[a];
      unsigned int u = xform(c.x);
      unsigned int k22 = u >> 10;
      if (k22 > key22){
        ce += softplus_(c.y - c.x);
      } else if (k22 == key22){
        unsigned int p = atomicAdd(&s_cnt, 1u);
        if (p < KC_CAP){ cu[p] = u; ci[p] = (unsigned int)a; }
      }
    }
  }
  for (int s=32;s>=1;s>>=1) ce += __shfl_down(ce, s);
  if (lane==0) wsum[wid] = ce;
  __syncthreads();
  if (t==0){
    float tot = 0.f;
    for (int w=0; w<16; w++) tot += wsum[w];
    unsigned int n = s_cnt < KC_CAP ? s_cnt : KC_CAP;
    for (unsigned int r=0; r<R2 && r<n; r++){
      unsigned int bu=0, bi=0xFFFFFFFFu; int bj=-1;
      for (unsigned int i2=0;i2<n;i2++){
        unsigned int uu = cu[i2];
        if (uu != 0 && (uu > bu || (uu==bu && ci[i2] < bi))){ bu=uu; bi=ci[i2]; bj=(int)i2; }
      }
      if (bj < 0) break;
      cu[bj] = 0;
      float2 c = cb[bi];
      tot += softplus_(c.y - c.x);
    }
    atomicAdd(&out[1], tot * cscale);
  }
}

extern "C" void kernel_launch(void* const* d_in, const int* in_sizes, int n_in,
                              void* d_out, int out_size, void* d_ws, size_t ws_size,
                              hipStream_t stream) {
  const float*  loc     = (const float*)d_in[0];
  const float2* conf    = (const float2*)d_in[1];
  const float4* anchors = (const float4*)d_in[2];
  const float*  targets = (const float*)d_in[3];
  int A = in_sizes[2] / 4;
  int B = in_sizes[0] / (A * 4);
  int O = in_sizes[3] / (B * 5);
  int K = 3 * O;
  float* out = (float*)d_out;
  ull* matchbest = (ull*)d_ws;
  ull* negmask = matchbest + (size_t)B*O;
  size_t wsneed = ((size_t)B*O + (size_t)B*(A>>6)) * sizeof(ull);
  hipMemsetAsync(d_ws, 0, wsneed, stream);
  hipMemsetAsync(d_out, 0, 2*sizeof(float), stream);

  dim3 gA(A/1024, B);
  kA<<<gA, 256, 0, stream>>>(anchors, targets, matchbest, negmask, A, O);

  int BO = B*O;
  float lscale = 1.0f / (float)BO;
  float cscale = 1.0f / ((float)(O+K) * (float)BO);
  kB<<<(BO+255)/256, 256, 0, stream>>>(loc, conf, targets, matchbest, out, A, O, BO, lscale, cscale);
  kC<<<B, 1024, 0, stream>>>(conf, negmask, out, A, K, cscale);
}

// Round 2
// 212.091 us; speedup vs baseline: 1.5059x; 1.5059x over previous
//
#include <hip/hip_runtime.h>
#include <hip/hip_bf16.h>
#include <math.h>

typedef unsigned long long ull;

#define MAXO 24

__device__ __forceinline__ unsigned int xform(float x){
  unsigned int b = __float_as_uint(x);
  return (b & 0x80000000u) ? ~b : (b | 0x80000000u);
}
__device__ __forceinline__ float softplus_(float d){
  return (d > 20.f) ? d : log1pf(expf(d));
}

// ---------------- Kernel A (specialized O=24): IoU, per-gt argmax, neg mask ----------
// Fully unrolled: biou/bidx stay in registers (rule #20 fix vs round 1).
template<int O>
__global__ __launch_bounds__(256) void kA_t(const float4* __restrict__ anchors,
        const float* __restrict__ targets,
        ull* __restrict__ matchbest, ull* __restrict__ negmask, int A){
  const int b = blockIdx.y, t = threadIdx.x, lane = t & 63;
  __shared__ ull wk[O][32];
  const float* tg = targets + (size_t)b * O * 5;
  const int base = blockIdx.x * 1024 + t;

  float ax1[4], ay1[4], ax2[4], ay2[4], aar[4], amax[4];
#pragma unroll
  for (int k = 0; k < 4; k++){
    float4 an = anchors[base + k*256];
    float hw = __fmul_rn(an.z, 0.5f), hh = __fmul_rn(an.w, 0.5f);
    ax1[k] = __fsub_rn(an.x, hw); ay1[k] = __fsub_rn(an.y, hh);
    ax2[k] = __fadd_rn(an.x, hw); ay2[k] = __fadd_rn(an.y, hh);
    aar[k] = __fmul_rn(__fsub_rn(ax2[k],ax1[k]), __fsub_rn(ay2[k],ay1[k]));
    amax[k] = 0.f;
  }

  unsigned int biou[O], bidx[O];
#pragma unroll
  for (int o = 0; o < O; o++){
    float gx1 = tg[o*5+0], gy1 = tg[o*5+1], gx2 = tg[o*5+2], gy2 = tg[o*5+3];
    float ga  = __fmul_rn(__fsub_rn(gx2,gx1), __fsub_rn(gy2,gy1));
    unsigned int bu = 0u, bi = 0u;
#pragma unroll
    for (int k = 0; k < 4; k++){
      float ltx = fmaxf(gx1, ax1[k]), lty = fmaxf(gy1, ay1[k]);
      float rbx = fminf(gx2, ax2[k]), rby = fminf(gy2, ay2[k]);
      float wx = fmaxf(__fsub_rn(rbx,ltx), 0.f);
      float wy = fmaxf(__fsub_rn(rby,lty), 0.f);
      float inter = __fmul_rn(wx, wy);
      float denom = __fsub_rn(__fadd_rn(ga, aar[k]), inter); // no FMA contraction
      float iou = __fdiv_rn(inter, denom);
      amax[k] = fmaxf(amax[k], iou);
      unsigned int ub = __float_as_uint(iou);  // iou>=0: bits are order-monotone
      bool better = ub > bu;                   // strict > + ascending k => first index
      bi = better ? (unsigned int)(base + k*256) : bi;
      bu = better ? ub : bu;
    }
    biou[o] = bu; bidx[o] = bi;
  }

#pragma unroll
  for (int k = 0; k < 4; k++){
    ull m = __ballot(amax[k] < 0.4f);
    if (lane == 0) negmask[(size_t)b*(A>>6) + ((unsigned)(base + k*256) >> 6)] = m;
  }

  // reduce per-gt (iou, idx) keys: 8-lane shuffle tree -> LDS -> 8-lane tree -> atomicMax
#pragma unroll
  for (int o = 0; o < O; o++){
    ull key = ((ull)biou[o] << 32) | (unsigned int)(~bidx[o]);
#pragma unroll
    for (int s = 4; s >= 1; s >>= 1){
      ull other = (ull)__shfl_down((long long)key, (unsigned)s, 8);
      if (other > key) key = other;
    }
    if ((lane & 7) == 0) wk[o][t >> 3] = key;
  }
  __syncthreads();
  if (t < O * 8){
    int o = t >> 3, part = t & 7;
    ull k = wk[o][part*4];
#pragma unroll
    for (int j = 1; j < 4; j++){ ull v = wk[o][part*4 + j]; if (v > k) k = v; }
#pragma unroll
    for (int s = 4; s >= 1; s >>= 1){
      ull other = (ull)__shfl_down((long long)k, (unsigned)s, 8);
      if (other > k) k = other;
    }
    if (part == 0) atomicMax(&matchbest[b*O + o], k);
  }
}

// Generic fallback (runtime O; spills, correct) — only used if O != 24.
__global__ __launch_bounds__(256) void kA_g(const float4* __restrict__ anchors,
        const float* __restrict__ targets,
        ull* __restrict__ matchbest, ull* __restrict__ negmask, int A, int O){
  int b = blockIdx.y, t = threadIdx.x, lane = t & 63, wid = t >> 6;
  __shared__ float sgt[MAXO*5];
  __shared__ float sarea[MAXO];
  __shared__ ull wk[4][MAXO];
  int n5 = O*5;
  if (t < n5) sgt[t] = targets[b*n5 + t];
  __syncthreads();
  if (t < O){
    float x1=sgt[t*5], y1=sgt[t*5+1], x2=sgt[t*5+2], y2=sgt[t*5+3];
    sarea[t] = __fmul_rn(__fsub_rn(x2,x1), __fsub_rn(y2,y1));
  }
  __syncthreads();
  ull key[MAXO];
  for (int o=0;o<O;o++) key[o]=0;
  int base = blockIdx.x * 1024;
  for (int k=0;k<4;k++){
    int a = base + k*256 + t;
    float4 an = anchors[a];
    float hw = __fmul_rn(an.z, 0.5f), hh = __fmul_rn(an.w, 0.5f);
    float ax1 = __fsub_rn(an.x, hw), ay1 = __fsub_rn(an.y, hh);
    float ax2 = __fadd_rn(an.x, hw), ay2 = __fadd_rn(an.y, hh);
    float aarea = __fmul_rn(__fsub_rn(ax2,ax1), __fsub_rn(ay2,ay1));
    float amax = 0.f;
    for (int o=0;o<O;o++){
      float ltx = fmaxf(sgt[o*5+0], ax1), lty = fmaxf(sgt[o*5+1], ay1);
      float rbx = fminf(sgt[o*5+2], ax2), rby = fminf(sgt[o*5+3], ay2);
      float wx = fmaxf(__fsub_rn(rbx,ltx), 0.f);
      float wy = fmaxf(__fsub_rn(rby,lty), 0.f);
      float inter = __fmul_rn(wx, wy);
      float denom = __fsub_rn(__fadd_rn(sarea[o], aarea), inter);
      float iou = __fdiv_rn(inter, denom);
      amax = fmaxf(amax, iou);
      ull kk = ((ull)__float_as_uint(iou) << 32) | (unsigned int)(~(unsigned int)a);
      if (kk > key[o]) key[o] = kk;
    }
    ull m = __ballot(amax < 0.4f);
    if (lane == 0) negmask[(size_t)b*(A>>6) + (a>>6)] = m;
  }
  for (int o=0;o<O;o++){
    ull k = key[o];
    for (int s=32; s>=1; s>>=1){
      unsigned int lo = __shfl_down((unsigned int)(k & 0xFFFFFFFFu), s);
      unsigned int hi = __shfl_down((unsigned int)(k >> 32), s);
      ull other = ((ull)hi<<32) | lo;
      if (other > k) k = other;
    }
    if (lane == 0) wk[wid][o] = k;
  }
  __syncthreads();
  if (t < O){
    ull k = wk[0][t];
    for (int w=1; w<4; w++){ ull v = wk[w][t]; if (v>k) k=v; }
    atomicMax(&matchbest[b*O + t], k);
  }
}

// ---------------- Kernel B: positive loc loss + positive CE ----------------
__global__ void kB(const float* __restrict__ loc, const float2* __restrict__ conf,
       const float* __restrict__ targets, const ull* __restrict__ matchbest,
       float* __restrict__ out, int A, int O, int BO, float lscale, float cscale){
  int i = blockIdx.x*blockDim.x + threadIdx.x;
  if (i >= BO) return;
  int b = i / O;
  ull key = matchbest[i];
  unsigned int idx = ~(unsigned int)(key & 0xFFFFFFFFull);
  const float* tg = targets + (size_t)i*5;
  const float* lp = loc + ((size_t)b*A + idx)*4;
  float ll = 0.f;
#pragma unroll
  for (int d=0; d<4; d++){
    float df = lp[d] - tg[d];
    float ad = fabsf(df);
    ll += (ad < 1.f) ? 0.5f*df*df : (ad - 0.5f);
  }
  float2 c = conf[(size_t)b*A + idx];
  float m = fmaxf(c.x, c.y);
  float lse = m + logf(expf(c.x - m) + expf(c.y - m));
  float ce = lse - c.y;   // label = 1
  atomicAdd(&out[0], ll * lscale);
  atomicAdd(&out[1], ce * cscale);
}

// ---------------- Hard-negative mining, parallel chain ----------------
// kH1: coarse 2048-bin histogram of xform(conf.x)>>21 over eligible anchors
__global__ __launch_bounds__(256) void kH1(const float2* __restrict__ conf,
     const ull* __restrict__ negmask, unsigned int* __restrict__ gh1, int A){
  int b = blockIdx.x, seg = blockIdx.y, t = threadIdx.x, lane = t & 63;
  __shared__ unsigned int h[2048];
  for (int i = t; i < 2048; i += 256) h[i] = 0;
  __syncthreads();
  const float2* cb = conf + (size_t)b * A;
  const ull* mb = negmask + (size_t)b * (A >> 6);
  int base = seg * 8192;
  for (int j = 0; j < 32; j++){
    int a = base + j*256 + t;
    ull w = mb[a >> 6];               // wave-uniform word
    if ((w >> lane) & 1ull){
      unsigned int u = xform(cb[a].x);
      atomicAdd(&h[u >> 21], 1u);
    }
  }
  __syncthreads();
  for (int i = t; i < 2048; i += 256){
    unsigned int v = h[i];
    if (v) atomicAdd(&gh1[b*2048 + i], v);
  }
}

// kT1: suffix-scan histogram, find boundary bin b1 and residual R
__global__ __launch_bounds__(256) void kT1(const unsigned int* __restrict__ gh1,
     unsigned int* __restrict__ thr, int K){
  int b = blockIdx.x, t = threadIdx.x;
  __shared__ unsigned int s0[2048], s1[2048];
  for (int i = t; i < 2048; i += 256) s0[i] = gh1[b*2048 + i];
  __syncthreads();
  unsigned int* src = s0; unsigned int* dst = s1;
  for (int d = 1; d < 2048; d <<= 1){
    for (int i = t; i < 2048; i += 256){
      unsigned int v = src[i];
      if (i + d < 2048) v += src[i + d];
      dst[i] = v;
    }
    __syncthreads();
    unsigned int* tmp = src; src = dst; dst = tmp;
  }
  for (int i = t; i < 2048; i += 256){
    unsigned int si = src[i];
    unsigned int sn = (i < 2047) ? src[i+1] : 0u;
    if (si >= (unsigned int)K && sn < (unsigned int)K){
      thr[b*2]   = (unsigned int)i;
      thr[b*2+1] = (unsigned int)K - sn;
    }
  }
}

// kF: CE of definite winners (bin > b1); collect boundary bin into glist
__global__ __launch_bounds__(256) void kF(const float2* __restrict__ conf,
     const ull* __restrict__ negmask, const unsigned int* __restrict__ thr,
     unsigned int* __restrict__ gcnt, ull* __restrict__ glist,
     float* __restrict__ out, int A, float cscale){
  int b = blockIdx.x, seg = blockIdx.y, t = threadIdx.x, lane = t & 63, wid = t >> 6;
  __shared__ float wsum[4];
  unsigned int b1 = thr[b*2];
  const float2* cb = conf + (size_t)b * A;
  const ull* mb = negmask + (size_t)b * (A >> 6);
  int base = seg * 8192;
  float ce = 0.f;
  for (int j = 0; j < 32; j++){
    int a = base + j*256 + t;
    ull w = mb[a >> 6];
    if ((w >> lane) & 1ull){
      float2 c = cb[a];
      unsigned int u = xform(c.x);
      unsigned int bin = u >> 21;
      if (bin > b1){
        ce += softplus_(c.y - c.x);
      } else if (bin == b1){
        unsigned int p = atomicAdd(&gcnt[b], 1u);
        if (p < 2048u) glist[(size_t)b*2048 + p] = ((ull)u << 32) | (unsigned int)(~(unsigned int)a);
      }
    }
  }
  for (int s = 32; s >= 1; s >>= 1) ce += __shfl_down(ce, s);
  if (lane == 0) wsum[wid] = ce;
  __syncthreads();
  if (t == 0){
    float tot = wsum[0] + wsum[1] + wsum[2] + wsum[3];
    atomicAdd(&out[1], tot * cscale);
  }
}

// kR: exact top-R within boundary bin via rank counting (value desc, index asc)
__global__ __launch_bounds__(64) void kR(const float2* __restrict__ conf,
     const ull* __restrict__ glist, const unsigned int* __restrict__ gcnt,
     const unsigned int* __restrict__ thr, float* __restrict__ out,
     int A, float cscale){
  int b = blockIdx.x, t = threadIdx.x;
  __shared__ ull sl[2048];
  unsigned int n = gcnt[b]; if (n > 2048u) n = 2048u;
  unsigned int R = thr[b*2+1];
  for (unsigned int i = t; i < n; i += 64) sl[i] = glist[(size_t)b*2048 + i];
  __syncthreads();
  float ce = 0.f;
  for (unsigned int i = t; i < n; i += 64){
    ull ki = sl[i];
    unsigned int rank = 0;
    for (unsigned int j = 0; j < n; j++) rank += (sl[j] > ki) ? 1u : 0u;
    if (rank < R){
      unsigned int a = ~(unsigned int)(ki & 0xFFFFFFFFull);
      float2 c = conf[(size_t)b*A + a];
      ce += softplus_(c.y - c.x);
    }
  }
  for (int s = 32; s >= 1; s >>= 1) ce += __shfl_down(ce, s);
  if (t == 0) atomicAdd(&out[1], ce * cscale);
}

extern "C" void kernel_launch(void* const* d_in, const int* in_sizes, int n_in,
                              void* d_out, int out_size, void* d_ws, size_t ws_size,
                              hipStream_t stream) {
  const float*  loc     = (const float*)d_in[0];
  const float2* conf    = (const float2*)d_in[1];
  const float4* anchors = (const float4*)d_in[2];
  const float*  targets = (const float*)d_in[3];
  int A = in_sizes[2] / 4;
  int B = in_sizes[0] / (A * 4);
  int O = in_sizes[3] / (B * 5);
  int K = 3 * O;
  float* out = (float*)d_out;

  char* wsb = (char*)d_ws;
  size_t off = 0;
  ull* matchbest = (ull*)(wsb + off);          off += (size_t)B * O * sizeof(ull);
  unsigned int* gh1  = (unsigned int*)(wsb + off); off += (size_t)B * 2048 * 4;
  unsigned int* gcnt = (unsigned int*)(wsb + off); off += (size_t)B * 4;
  unsigned int* thr  = (unsigned int*)(wsb + off); off += (size_t)B * 2 * 4;
  size_t zbytes = off;
  off = (off + 7) & ~(size_t)7;
  ull* negmask = (ull*)(wsb + off);            off += (size_t)B * (A >> 6) * sizeof(ull);
  ull* glist   = (ull*)(wsb + off);            off += (size_t)B * 2048 * sizeof(ull);

  hipMemsetAsync(d_ws, 0, zbytes, stream);
  hipMemsetAsync(d_out, 0, 2*sizeof(float), stream);

  dim3 gA(A/1024, B);
  if (O == 24) kA_t<24><<<gA, 256, 0, stream>>>(anchors, targets, matchbest, negmask, A);
  else         kA_g<<<gA, 256, 0, stream>>>(anchors, targets, matchbest, negmask, A, O);

  int BO = B*O;
  float lscale = 1.0f / (float)BO;
  float cscale = 1.0f / ((float)(O+K) * (float)BO);
  kB<<<(BO+255)/256, 256, 0, stream>>>(loc, conf, targets, matchbest, out, A, O, BO, lscale, cscale);

  dim3 gS(B, A/8192);
  kH1<<<gS, 256, 0, stream>>>(conf, negmask, gh1, A);
  kT1<<<B, 256, 0, stream>>>(gh1, thr, K);
  kF<<<gS, 256, 0, stream>>>(conf, negmask, thr, gcnt, glist, out, A, cscale);
  kR<<<B, 64, 0, stream>>>(conf, glist, gcnt, thr, out, A, cscale);
}

// Round 3
// 189.268 us; speedup vs baseline: 1.6875x; 1.1206x over previous
//
#include <hip/hip_runtime.h>
#include <hip/hip_bf16.h>
#include <math.h>

typedef unsigned long long ull;

#define MAXO 24

__device__ __forceinline__ unsigned int xform(float x){
  unsigned int b = __float_as_uint(x);
  return (b & 0x80000000u) ? ~b : (b | 0x80000000u);
}
__device__ __forceinline__ float softplus_(float d){
  return (d > 20.f) ? d : log1pf(expf(d));
}

// ------- Kernel A (O=24): IoU argmax per gt, neg mask, conf histogram -------
template<int O>
__global__ __launch_bounds__(256) void kA_t(const float4* __restrict__ anchors,
        const float* __restrict__ targets, const float2* __restrict__ conf,
        ull* __restrict__ matchbest, ull* __restrict__ negmask,
        unsigned int* __restrict__ gh1, int A){
  const int b = blockIdx.y, t = threadIdx.x, lane = t & 63;
  __shared__ ull wk[O][32];
  __shared__ unsigned int hist[2048];
  for (int i = t; i < 2048; i += 256) hist[i] = 0;
  __syncthreads();
  const float* tg = targets + (size_t)b * O * 5;
  const int base = blockIdx.x * 1024 + t;

  float ax1[4], ay1[4], ax2[4], ay2[4], aar[4], amax[4];
#pragma unroll
  for (int k = 0; k < 4; k++){
    float4 an = anchors[base + k*256];
    float hw = __fmul_rn(an.z, 0.5f), hh = __fmul_rn(an.w, 0.5f);
    ax1[k] = __fsub_rn(an.x, hw); ay1[k] = __fsub_rn(an.y, hh);
    ax2[k] = __fadd_rn(an.x, hw); ay2[k] = __fadd_rn(an.y, hh);
    aar[k] = __fmul_rn(__fsub_rn(ax2[k],ax1[k]), __fsub_rn(ay2[k],ay1[k]));
    amax[k] = 0.f;
  }

  unsigned int biou[O], bidx[O];
#pragma unroll
  for (int o = 0; o < O; o++){
    float gx1 = tg[o*5+0], gy1 = tg[o*5+1], gx2 = tg[o*5+2], gy2 = tg[o*5+3];
    float ga  = __fmul_rn(__fsub_rn(gx2,gx1), __fsub_rn(gy2,gy1));
    unsigned int bu = 0u, bi = 0u;
#pragma unroll
    for (int k = 0; k < 4; k++){
      float ltx = fmaxf(gx1, ax1[k]), lty = fmaxf(gy1, ay1[k]);
      float rbx = fminf(gx2, ax2[k]), rby = fminf(gy2, ay2[k]);
      float wx = fmaxf(__fsub_rn(rbx,ltx), 0.f);
      float wy = fmaxf(__fsub_rn(rby,lty), 0.f);
      float inter = __fmul_rn(wx, wy);
      float denom = __fsub_rn(__fadd_rn(ga, aar[k]), inter); // keep rn, no FMA contraction
      float iou = __fmul_rn(inter, __builtin_amdgcn_rcpf(denom)); // fast rcp: argmax/0.4-mask only
      amax[k] = fmaxf(amax[k], iou);
      unsigned int ub = __float_as_uint(iou);  // iou>=0: bit pattern order-monotone
      bool better = ub > bu;                   // strict > + ascending k => first index wins
      bi = better ? (unsigned int)(base + k*256) : bi;
      bu = better ? ub : bu;
    }
    biou[o] = bu; bidx[o] = bi;
  }

#pragma unroll
  for (int k = 0; k < 4; k++){
    bool neg = amax[k] < 0.4f;
    ull m = __ballot(neg);
    if (lane == 0) negmask[(size_t)b*(A>>6) + ((unsigned)(base + k*256) >> 6)] = m;
    if (neg){
      float cx = conf[(size_t)b*A + (unsigned)(base + k*256)].x;
      atomicAdd(&hist[xform(cx) >> 21], 1u);
    }
  }

  // reduce per-gt (iou, idx): 8-lane shuffle tree -> LDS -> 8-lane tree -> atomicMax
#pragma unroll
  for (int o = 0; o < O; o++){
    ull key = ((ull)biou[o] << 32) | (unsigned int)(~bidx[o]);
#pragma unroll
    for (int s = 4; s >= 1; s >>= 1){
      ull other = (ull)__shfl_down((long long)key, (unsigned)s, 8);
      if (other > key) key = other;
    }
    if ((lane & 7) == 0) wk[o][t >> 3] = key;
  }
  __syncthreads();   // orders wk writes AND all hist atomics
  if (t < O * 8){
    int o = t >> 3, part = t & 7;
    ull k = wk[o][part*4];
#pragma unroll
    for (int j = 1; j < 4; j++){ ull v = wk[o][part*4 + j]; if (v > k) k = v; }
#pragma unroll
    for (int s = 4; s >= 1; s >>= 1){
      ull other = (ull)__shfl_down((long long)k, (unsigned)s, 8);
      if (other > k) k = other;
    }
    if (part == 0) atomicMax(&matchbest[b*O + o], k);
  }
  // flush block-local histogram
  for (int i = t; i < 2048; i += 256){
    unsigned int v = hist[i];
    if (v) atomicAdd(&gh1[b*2048 + i], v);
  }
}

// ------- Generic fallbacks (O != 24 path) -------
__global__ __launch_bounds__(256) void kA_g(const float4* __restrict__ anchors,
        const float* __restrict__ targets,
        ull* __restrict__ matchbest, ull* __restrict__ negmask, int A, int O){
  int b = blockIdx.y, t = threadIdx.x, lane = t & 63, wid = t >> 6;
  __shared__ float sgt[MAXO*5];
  __shared__ float sarea[MAXO];
  __shared__ ull wk[4][MAXO];
  int n5 = O*5;
  if (t < n5) sgt[t] = targets[b*n5 + t];
  __syncthreads();
  if (t < O){
    float x1=sgt[t*5], y1=sgt[t*5+1], x2=sgt[t*5+2], y2=sgt[t*5+3];
    sarea[t] = __fmul_rn(__fsub_rn(x2,x1), __fsub_rn(y2,y1));
  }
  __syncthreads();
  ull key[MAXO];
  for (int o=0;o<O;o++) key[o]=0;
  int base = blockIdx.x * 1024;
  for (int k=0;k<4;k++){
    int a = base + k*256 + t;
    float4 an = anchors[a];
    float hw = __fmul_rn(an.z, 0.5f), hh = __fmul_rn(an.w, 0.5f);
    float ax1 = __fsub_rn(an.x, hw), ay1 = __fsub_rn(an.y, hh);
    float ax2 = __fadd_rn(an.x, hw), ay2 = __fadd_rn(an.y, hh);
    float aarea = __fmul_rn(__fsub_rn(ax2,ax1), __fsub_rn(ay2,ay1));
    float amax = 0.f;
    for (int o=0;o<O;o++){
      float ltx = fmaxf(sgt[o*5+0], ax1), lty = fmaxf(sgt[o*5+1], ay1);
      float rbx = fminf(sgt[o*5+2], ax2), rby = fminf(sgt[o*5+3], ay2);
      float wx = fmaxf(__fsub_rn(rbx,ltx), 0.f);
      float wy = fmaxf(__fsub_rn(rby,lty), 0.f);
      float inter = __fmul_rn(wx, wy);
      float denom = __fsub_rn(__fadd_rn(sarea[o], aarea), inter);
      float iou = __fdiv_rn(inter, denom);
      amax = fmaxf(amax, iou);
      ull kk = ((ull)__float_as_uint(iou) << 32) | (unsigned int)(~(unsigned int)a);
      if (kk > key[o]) key[o] = kk;
    }
    ull m = __ballot(amax < 0.4f);
    if (lane == 0) negmask[(size_t)b*(A>>6) + (a>>6)] = m;
  }
  for (int o=0;o<O;o++){
    ull k = key[o];
    for (int s=32; s>=1; s>>=1){
      unsigned int lo = __shfl_down((unsigned int)(k & 0xFFFFFFFFu), s);
      unsigned int hi = __shfl_down((unsigned int)(k >> 32), s);
      ull other = ((ull)hi<<32) | lo;
      if (other > k) k = other;
    }
    if (lane == 0) wk[wid][o] = k;
  }
  __syncthreads();
  if (t < O){
    ull k = wk[0][t];
    for (int w=1; w<4; w++){ ull v = wk[w][t]; if (v>k) k=v; }
    atomicMax(&matchbest[b*O + t], k);
  }
}

__global__ __launch_bounds__(256) void kH1(const float2* __restrict__ conf,
     const ull* __restrict__ negmask, unsigned int* __restrict__ gh1, int A){
  int b = blockIdx.x, seg = blockIdx.y, t = threadIdx.x, lane = t & 63;
  __shared__ unsigned int h[2048];
  for (int i = t; i < 2048; i += 256) h[i] = 0;
  __syncthreads();
  const float2* cb = conf + (size_t)b * A;
  const ull* mb = negmask + (size_t)b * (A >> 6);
  int base = seg * 8192;
  for (int j = 0; j < 32; j++){
    int a = base + j*256 + t;
    ull w = mb[a >> 6];
    if ((w >> lane) & 1ull){
      unsigned int u = xform(cb[a].x);
      atomicAdd(&h[u >> 21], 1u);
    }
  }
  __syncthreads();
  for (int i = t; i < 2048; i += 256){
    unsigned int v = h[i];
    if (v) atomicAdd(&gh1[b*2048 + i], v);
  }
}

// ------- kM2: per-image. positives + threshold + winners-CE + exact boundary -------
__global__ __launch_bounds__(1024) void kM2(const float2* __restrict__ conf,
     const ull* __restrict__ negmask, const unsigned int* __restrict__ gh1,
     const ull* __restrict__ matchbest, const float* __restrict__ loc,
     const float* __restrict__ targets, float* __restrict__ out,
     int A, int O, int K, float lscale, float cscale){
  const int b = blockIdx.x, t = threadIdx.x, lane = t & 63, wid = t >> 6;
  __shared__ unsigned int s0[2048], s1[2048];
  __shared__ ull stash[2048];
  __shared__ ull sb[256];
  __shared__ unsigned int s_cnt, s_cnt2, s_b1, s_R, s_b2, s_R2;
  __shared__ float wsum[16];

  // positives (former kB)
  if (t < O){
    int i = b*O + t;
    ull key = matchbest[i];
    unsigned int idx = ~(unsigned int)(key & 0xFFFFFFFFull);
    const float* tg = targets + (size_t)i*5;
    const float* lp = loc + ((size_t)b*A + idx)*4;
    float ll = 0.f;
#pragma unroll
    for (int d=0; d<4; d++){
      float df = lp[d] - tg[d];
      float ad = fabsf(df);
      ll += (ad < 1.f) ? 0.5f*df*df : (ad - 0.5f);
    }
    float2 c = conf[(size_t)b*A + idx];
    float m = fmaxf(c.x, c.y);
    float lse = m + logf(expf(c.x - m) + expf(c.y - m));
    atomicAdd(&out[0], ll * lscale);
    atomicAdd(&out[1], (lse - c.y) * cscale);
  }
  if (t == 0){ s_cnt = 0; s_cnt2 = 0; }
  for (int i = t; i < 2048; i += 1024) s0[i] = gh1[b*2048 + i];
  __syncthreads();

  // suffix scan -> (b1, R)
  {
    unsigned int* src = s0; unsigned int* dst = s1;
    for (int d = 1; d < 2048; d <<= 1){
      for (int i = t; i < 2048; i += 1024){
        unsigned int v = src[i];
        if (i + d < 2048) v += src[i + d];
        dst[i] = v;
      }
      __syncthreads();
      unsigned int* tmp = src; src = dst; dst = tmp;
    }
    for (int i = t; i < 2048; i += 1024){
      unsigned int si = src[i];
      unsigned int sn = (i < 2047) ? src[i+1] : 0u;
      if (si >= (unsigned int)K && sn < (unsigned int)K){ s_b1 = (unsigned int)i; s_R = (unsigned int)K - sn; }
    }
  }
  __syncthreads();
  const unsigned int b1 = s_b1, R = s_R;
  for (int i = t; i < 2048; i += 1024) s0[i] = 0;   // s0 becomes level-2 histogram
  __syncthreads();

  // main pass: winners CE + refine-hist + stash boundary bin
  float ce = 0.f;
  const float2* cb = conf + (size_t)b * A;
  const ull* mb = negmask + (size_t)b * (A >> 6);
  const int iters = A >> 10;
  for (int j = 0; j < iters; j++){
    int a = (j << 10) + t;
    ull w = mb[a >> 6];
    if ((w >> (a & 63)) & 1ull){
      float2 c = cb[a];
      unsigned int u = xform(c.x);
      unsigned int bin = u >> 21;
      if (bin > b1){
        ce += softplus_(c.y - c.x);
      } else if (bin == b1){
        atomicAdd(&s0[(u >> 10) & 2047u], 1u);
        unsigned int p = atomicAdd(&s_cnt, 1u);
        if (p < 2048u) stash[p] = ((ull)u << 32) | (unsigned int)(~(unsigned int)a);
      }
    }
  }
  __syncthreads();

  // suffix scan level-2 -> (b2, R2)
  {
    unsigned int* src = s0; unsigned int* dst = s1;
    for (int d = 1; d < 2048; d <<= 1){
      for (int i = t; i < 2048; i += 1024){
        unsigned int v = src[i];
        if (i + d < 2048) v += src[i + d];
        dst[i] = v;
      }
      __syncthreads();
      unsigned int* tmp = src; src = dst; dst = tmp;
    }
    for (int i = t; i < 2048; i += 1024){
      unsigned int si = src[i];
      unsigned int sn = (i < 2047) ? src[i+1] : 0u;
      if (si >= R && sn < R){ s_b2 = (unsigned int)i; s_R2 = R - sn; }
    }
  }
  __syncthreads();
  const unsigned int b2 = s_b2, R2 = s_R2;
  const unsigned int cnt = (s_cnt < 2048u) ? s_cnt : 2048u;
  const bool ovf = (s_cnt > 2048u);

  if (!ovf){
    for (unsigned int i = t; i < cnt; i += 1024){
      ull e = stash[i];
      unsigned int u = (unsigned int)(e >> 32);
      unsigned int sub = (u >> 10) & 2047u;
      if (sub > b2){
        unsigned int a = ~(unsigned int)(e & 0xFFFFFFFFull);
        float2 c = cb[a];
        ce += softplus_(c.y - c.x);
      } else if (sub == b2){
        unsigned int p = atomicAdd(&s_cnt2, 1u);
        if (p < 256u) sb[p] = e;
      }
    }
  } else {
    // stash overflow (pathological input): re-scan for bin==b1
    for (int j = 0; j < iters; j++){
      int a = (j << 10) + t;
      ull w = mb[a >> 6];
      if ((w >> (a & 63)) & 1ull){
        float2 c = cb[a];
        unsigned int u = xform(c.x);
        if ((u >> 21) == b1){
          unsigned int sub = (u >> 10) & 2047u;
          if (sub > b2){
            ce += softplus_(c.y - c.x);
          } else if (sub == b2){
            unsigned int p = atomicAdd(&s_cnt2, 1u);
            if (p < 256u) sb[p] = ((ull)u << 32) | (unsigned int)(~(unsigned int)a);
          }
        }
      }
    }
  }
  __syncthreads();

  // exact rank on tiny 22-bit-equal bucket (value desc, index asc via ~a)
  const unsigned int cnt2 = (s_cnt2 < 256u) ? s_cnt2 : 256u;
  for (unsigned int i = t; i < cnt2; i += 1024){
    ull ki = sb[i];
    unsigned int rank = 0;
    for (unsigned int j = 0; j < cnt2; j++) rank += (sb[j] > ki) ? 1u : 0u;
    if (rank < R2){
      unsigned int a = ~(unsigned int)(ki & 0xFFFFFFFFull);
      float2 c = cb[a];
      ce += softplus_(c.y - c.x);
    }
  }

  // block reduce ce
#pragma unroll
  for (int s = 32; s >= 1; s >>= 1) ce += __shfl_down(ce, s);
  if (lane == 0) wsum[wid] = ce;
  __syncthreads();
  if (t == 0){
    float tot = 0.f;
    for (int w2 = 0; w2 < 16; w2++) tot += wsum[w2];
    atomicAdd(&out[1], tot * cscale);
  }
}

extern "C" void kernel_launch(void* const* d_in, const int* in_sizes, int n_in,
                              void* d_out, int out_size, void* d_ws, size_t ws_size,
                              hipStream_t stream) {
  const float*  loc     = (const float*)d_in[0];
  const float2* conf    = (const float2*)d_in[1];
  const float4* anchors = (const float4*)d_in[2];
  const float*  targets = (const float*)d_in[3];
  int A = in_sizes[2] / 4;
  int B = in_sizes[0] / (A * 4);
  int O = in_sizes[3] / (B * 5);
  int K = 3 * O;
  float* out = (float*)d_out;

  char* wsb = (char*)d_ws;
  size_t off = 0;
  ull* matchbest = (ull*)(wsb + off);              off += (size_t)B * O * sizeof(ull);
  unsigned int* gh1 = (unsigned int*)(wsb + off);  off += (size_t)B * 2048 * 4;
  size_t zbytes = off;
  off = (off + 7) & ~(size_t)7;
  ull* negmask = (ull*)(wsb + off);                off += (size_t)B * (A >> 6) * sizeof(ull);

  hipMemsetAsync(d_ws, 0, zbytes, stream);
  hipMemsetAsync(d_out, 0, 2*sizeof(float), stream);

  float lscale = 1.0f / (float)(B*O);
  float cscale = 1.0f / ((float)(O+K) * (float)(B*O));

  dim3 gA(A/1024, B);
  if (O == 24){
    kA_t<24><<<gA, 256, 0, stream>>>(anchors, targets, conf, matchbest, negmask, gh1, A);
  } else {
    kA_g<<<gA, 256, 0, stream>>>(anchors, targets, matchbest, negmask, A, O);
    dim3 gS(B, A/8192);
    kH1<<<gS, 256, 0, stream>>>(conf, negmask, gh1, A);
  }
  kM2<<<B, 1024, 0, stream>>>(conf, negmask, gh1, matchbest, loc, targets, out,
                              A, O, K, lscale, cscale);
}

// Round 4
// 174.698 us; speedup vs baseline: 1.8282x; 1.0834x over previous
//
#include <hip/hip_runtime.h>
#include <hip/hip_bf16.h>
#include <math.h>

typedef unsigned long long ull;

#define MAXO 24
#define GCAP 2048u

__device__ __forceinline__ unsigned int xform(float x){
  unsigned int b = __float_as_uint(x);
  return (b & 0x80000000u) ? ~b : (b | 0x80000000u);
}
__device__ __forceinline__ float softplus_(float d){
  return (d > 20.f) ? d : log1pf(expf(d));
}

// ------- Kernel A (O=24): IoU argmax per gt, neg mask, conf histogram -------
template<int O>
__global__ __launch_bounds__(256) void kA_t(const float4* __restrict__ anchors,
        const float* __restrict__ targets, const float2* __restrict__ conf,
        ull* __restrict__ matchbest, ull* __restrict__ negmask,
        unsigned int* __restrict__ gh1, int A){
  const int b = blockIdx.y, t = threadIdx.x, lane = t & 63;
  __shared__ ull wk[O][32];
  __shared__ unsigned int hist[2048];
  for (int i = t; i < 2048; i += 256) hist[i] = 0;
  __syncthreads();
  const float* tg = targets + (size_t)b * O * 5;
  const int base = blockIdx.x * 1024 + t;

  float ax1[4], ay1[4], ax2[4], ay2[4], aar[4], amax[4];
#pragma unroll
  for (int k = 0; k < 4; k++){
    float4 an = anchors[base + k*256];
    float hw = __fmul_rn(an.z, 0.5f), hh = __fmul_rn(an.w, 0.5f);
    ax1[k] = __fsub_rn(an.x, hw); ay1[k] = __fsub_rn(an.y, hh);
    ax2[k] = __fadd_rn(an.x, hw); ay2[k] = __fadd_rn(an.y, hh);
    aar[k] = __fmul_rn(__fsub_rn(ax2[k],ax1[k]), __fsub_rn(ay2[k],ay1[k]));
    amax[k] = 0.f;
  }

  unsigned int biou[O], bidx[O];
#pragma unroll
  for (int o = 0; o < O; o++){
    float gx1 = tg[o*5+0], gy1 = tg[o*5+1], gx2 = tg[o*5+2], gy2 = tg[o*5+3];
    float ga  = __fmul_rn(__fsub_rn(gx2,gx1), __fsub_rn(gy2,gy1));
    unsigned int bu = 0u, bi = 0u;
#pragma unroll
    for (int k = 0; k < 4; k++){
      float ltx = fmaxf(gx1, ax1[k]), lty = fmaxf(gy1, ay1[k]);
      float rbx = fminf(gx2, ax2[k]), rby = fminf(gy2, ay2[k]);
      float wx = fmaxf(__fsub_rn(rbx,ltx), 0.f);
      float wy = fmaxf(__fsub_rn(rby,lty), 0.f);
      float inter = __fmul_rn(wx, wy);
      float denom = __fsub_rn(__fadd_rn(ga, aar[k]), inter);
      float iou = __fmul_rn(inter, __builtin_amdgcn_rcpf(denom)); // argmax/mask only
      amax[k] = fmaxf(amax[k], iou);
      unsigned int ub = __float_as_uint(iou);
      bool better = ub > bu;                   // strict > + ascending k => first index
      bi = better ? (unsigned int)(base + k*256) : bi;
      bu = better ? ub : bu;
    }
    biou[o] = bu; bidx[o] = bi;
  }

#pragma unroll
  for (int k = 0; k < 4; k++){
    bool neg = amax[k] < 0.4f;
    ull m = __ballot(neg);
    if (lane == 0) negmask[(size_t)b*(A>>6) + ((unsigned)(base + k*256) >> 6)] = m;
    if (neg){
      float cx = conf[(size_t)b*A + (unsigned)(base + k*256)].x;
      atomicAdd(&hist[xform(cx) >> 21], 1u);
    }
  }

#pragma unroll
  for (int o = 0; o < O; o++){
    ull key = ((ull)biou[o] << 32) | (unsigned int)(~bidx[o]);
#pragma unroll
    for (int s = 4; s >= 1; s >>= 1){
      ull other = (ull)__shfl_down((long long)key, (unsigned)s, 8);
      if (other > key) key = other;
    }
    if ((lane & 7) == 0) wk[o][t >> 3] = key;
  }
  __syncthreads();
  if (t < O * 8){
    int o = t >> 3, part = t & 7;
    ull k = wk[o][part*4];
#pragma unroll
    for (int j = 1; j < 4; j++){ ull v = wk[o][part*4 + j]; if (v > k) k = v; }
#pragma unroll
    for (int s = 4; s >= 1; s >>= 1){
      ull other = (ull)__shfl_down((long long)k, (unsigned)s, 8);
      if (other > k) k = other;
    }
    if (part == 0) atomicMax(&matchbest[b*O + o], k);
  }
  for (int i = t; i < 2048; i += 256){
    unsigned int v = hist[i];
    if (v) atomicAdd(&gh1[b*2048 + i], v);
  }
}

// ------- Generic fallback (O != 24) -------
__global__ __launch_bounds__(256) void kA_g(const float4* __restrict__ anchors,
        const float* __restrict__ targets,
        ull* __restrict__ matchbest, ull* __restrict__ negmask, int A, int O){
  int b = blockIdx.y, t = threadIdx.x, lane = t & 63, wid = t >> 6;
  __shared__ float sgt[MAXO*5];
  __shared__ float sarea[MAXO];
  __shared__ ull wk[4][MAXO];
  int n5 = O*5;
  if (t < n5) sgt[t] = targets[b*n5 + t];
  __syncthreads();
  if (t < O){
    float x1=sgt[t*5], y1=sgt[t*5+1], x2=sgt[t*5+2], y2=sgt[t*5+3];
    sarea[t] = __fmul_rn(__fsub_rn(x2,x1), __fsub_rn(y2,y1));
  }
  __syncthreads();
  ull key[MAXO];
  for (int o=0;o<O;o++) key[o]=0;
  int base = blockIdx.x * 1024;
  for (int k=0;k<4;k++){
    int a = base + k*256 + t;
    float4 an = anchors[a];
    float hw = __fmul_rn(an.z, 0.5f), hh = __fmul_rn(an.w, 0.5f);
    float ax1 = __fsub_rn(an.x, hw), ay1 = __fsub_rn(an.y, hh);
    float ax2 = __fadd_rn(an.x, hw), ay2 = __fadd_rn(an.y, hh);
    float aarea = __fmul_rn(__fsub_rn(ax2,ax1), __fsub_rn(ay2,ay1));
    float amax = 0.f;
    for (int o=0;o<O;o++){
      float ltx = fmaxf(sgt[o*5+0], ax1), lty = fmaxf(sgt[o*5+1], ay1);
      float rbx = fminf(sgt[o*5+2], ax2), rby = fminf(sgt[o*5+3], ay2);
      float wx = fmaxf(__fsub_rn(rbx,ltx), 0.f);
      float wy = fmaxf(__fsub_rn(rby,lty), 0.f);
      float inter = __fmul_rn(wx, wy);
      float denom = __fsub_rn(__fadd_rn(sarea[o], aarea), inter);
      float iou = __fdiv_rn(inter, denom);
      amax = fmaxf(amax, iou);
      ull kk = ((ull)__float_as_uint(iou) << 32) | (unsigned int)(~(unsigned int)a);
      if (kk > key[o]) key[o] = kk;
    }
    ull m = __ballot(amax < 0.4f);
    if (lane == 0) negmask[(size_t)b*(A>>6) + (a>>6)] = m;
  }
  for (int o=0;o<O;o++){
    ull k = key[o];
    for (int s=32; s>=1; s>>=1){
      unsigned int lo = __shfl_down((unsigned int)(k & 0xFFFFFFFFu), s);
      unsigned int hi = __shfl_down((unsigned int)(k >> 32), s);
      ull other = ((ull)hi<<32) | lo;
      if (other > k) k = other;
    }
    if (lane == 0) wk[wid][o] = k;
  }
  __syncthreads();
  if (t < O){
    ull k = wk[0][t];
    for (int w=1; w<4; w++){ ull v = wk[w][t]; if (v>k) k=v; }
    atomicMax(&matchbest[b*O + t], k);
  }
}

__global__ __launch_bounds__(256) void kH1(const float2* __restrict__ conf,
     const ull* __restrict__ negmask, unsigned int* __restrict__ gh1, int A){
  int b = blockIdx.x, seg = blockIdx.y, t = threadIdx.x, lane = t & 63;
  __shared__ unsigned int h[2048];
  for (int i = t; i < 2048; i += 256) h[i] = 0;
  __syncthreads();
  const float2* cb = conf + (size_t)b * A;
  const ull* mb = negmask + (size_t)b * (A >> 6);
  int base = seg * 8192;
  for (int j = 0; j < 32; j++){
    int a = base + j*256 + t;
    ull w = mb[a >> 6];
    if ((w >> lane) & 1ull){
      unsigned int u = xform(cb[a].x);
      atomicAdd(&h[u >> 21], 1u);
    }
  }
  __syncthreads();
  for (int i = t; i < 2048; i += 256){
    unsigned int v = h[i];
    if (v) atomicAdd(&gh1[b*2048 + i], v);
  }
}

// ------- kT1: per-image level-1 scan -> (b1,R); plus positive losses -------
__global__ __launch_bounds__(256) void kT1(const unsigned int* __restrict__ gh1,
     unsigned int* __restrict__ thr, const ull* __restrict__ matchbest,
     const float* __restrict__ loc, const float* __restrict__ targets,
     const float2* __restrict__ conf, float* __restrict__ out,
     int A, int O, int K, float lscale, float cscale){
  int b = blockIdx.x, t = threadIdx.x;
  __shared__ unsigned int s0[2048], s1[2048];
  if (t < O){
    int i = b*O + t;
    ull key = matchbest[i];
    unsigned int idx = ~(unsigned int)(key & 0xFFFFFFFFull);
    const float* tg = targets + (size_t)i*5;
    const float* lp = loc + ((size_t)b*A + idx)*4;
    float ll = 0.f;
#pragma unroll
    for (int d=0; d<4; d++){
      float df = lp[d] - tg[d];
      float ad = fabsf(df);
      ll += (ad < 1.f) ? 0.5f*df*df : (ad - 0.5f);
    }
    float2 c = conf[(size_t)b*A + idx];
    float m = fmaxf(c.x, c.y);
    float lse = m + logf(expf(c.x - m) + expf(c.y - m));
    atomicAdd(&out[0], ll * lscale);
    atomicAdd(&out[1], (lse - c.y) * cscale);
  }
  for (int i = t; i < 2048; i += 256) s0[i] = gh1[b*2048 + i];
  __syncthreads();
  unsigned int* src = s0; unsigned int* dst = s1;
  for (int d = 1; d < 2048; d <<= 1){
    for (int i = t; i < 2048; i += 256){
      unsigned int v = src[i];
      if (i + d < 2048) v += src[i + d];
      dst[i] = v;
    }
    __syncthreads();
    unsigned int* tmp = src; src = dst; dst = tmp;
  }
  for (int i = t; i < 2048; i += 256){
    unsigned int si = src[i];
    unsigned int sn = (i < 2047) ? src[i+1] : 0u;
    if (si >= (unsigned int)K && sn < (unsigned int)K){
      thr[b*2]   = (unsigned int)i;
      thr[b*2+1] = (unsigned int)K - sn;
    }
  }
}

// ------- kW: wide pass. winners CE + level-2 hist + boundary stash -------
__global__ __launch_bounds__(256) void kW(const float2* __restrict__ conf,
     const ull* __restrict__ negmask, const unsigned int* __restrict__ thr,
     unsigned int* __restrict__ gh2, unsigned int* __restrict__ gcnt,
     ull* __restrict__ glist, float* __restrict__ out, int A, float cscale){
  const int b = blockIdx.x, seg = blockIdx.y, t = threadIdx.x;
  const int lane = t & 63, wid = t >> 6;
  __shared__ unsigned int h2[2048];
  __shared__ float wsum[4];
  for (int i = t; i < 2048; i += 256) h2[i] = 0;
  __syncthreads();
  const unsigned int b1 = thr[b*2];
  const float2* cb = conf + (size_t)b * A;
  const ull* mb = negmask + (size_t)b * (A >> 6);
  const int base = seg * 2048;
  float ce = 0.f;
#pragma unroll
  for (int j = 0; j < 8; j++){
    int a = base + j*256 + t;
    ull w = mb[a >> 6];
    if ((w >> lane) & 1ull){
      float2 c = cb[a];
      unsigned int u = xform(c.x);
      unsigned int bin = u >> 21;
      if (bin > b1){
        ce += softplus_(c.y - c.x);
      } else if (bin == b1){
        atomicAdd(&h2[(u >> 10) & 2047u], 1u);
        unsigned int p = atomicAdd(&gcnt[b], 1u);
        if (p < GCAP) glist[(size_t)b*GCAP + p] = ((ull)u << 32) | (unsigned int)(~(unsigned int)a);
      }
    }
  }
#pragma unroll
  for (int s = 32; s >= 1; s >>= 1) ce += __shfl_down(ce, s);
  if (lane == 0) wsum[wid] = ce;
  __syncthreads();
  if (t == 0) atomicAdd(&out[1], (wsum[0]+wsum[1]+wsum[2]+wsum[3]) * cscale);
  for (int i = t; i < 2048; i += 256){
    unsigned int v = h2[i];
    if (v) atomicAdd(&gh2[b*2048 + i], v);
  }
}

// ------- kF2: level-2 scan, sub-bin winners, exact tiny rank -------
__global__ __launch_bounds__(256) void kF2(const float2* __restrict__ conf,
     const ull* __restrict__ negmask, const unsigned int* __restrict__ thr,
     const unsigned int* __restrict__ gh2, const unsigned int* __restrict__ gcnt,
     const ull* __restrict__ glist, float* __restrict__ out, int A, float cscale){
  const int b = blockIdx.x, t = threadIdx.x, lane = t & 63, wid = t >> 6;
  __shared__ unsigned int s0[2048], s1[2048];
  __shared__ ull sb[256];
  __shared__ unsigned int s_b2, s_R2, s_cnt2;
  __shared__ float wsum[4];
  const unsigned int b1 = thr[b*2];
  const unsigned int R  = thr[b*2+1];
  if (t == 0){ s_b2 = 0; s_R2 = R; s_cnt2 = 0; }
  for (int i = t; i < 2048; i += 256) s0[i] = gh2[b*2048 + i];
  __syncthreads();
  {
    unsigned int* src = s0; unsigned int* dst = s1;
    for (int d = 1; d < 2048; d <<= 1){
      for (int i = t; i < 2048; i += 256){
        unsigned int v = src[i];
        if (i + d < 2048) v += src[i + d];
        dst[i] = v;
      }
      __syncthreads();
      unsigned int* tmp = src; src = dst; dst = tmp;
    }
    for (int i = t; i < 2048; i += 256){
      unsigned int si = src[i];
      unsigned int sn = (i < 2047) ? src[i+1] : 0u;
      if (si >= R && sn < R){ s_b2 = (unsigned int)i; s_R2 = R - sn; }
    }
  }
  __syncthreads();
  const unsigned int b2 = s_b2, R2 = s_R2;
  const unsigned int rawcnt = gcnt[b];
  const unsigned int cnt = (rawcnt < GCAP) ? rawcnt : GCAP;
  const bool ovf = (rawcnt > GCAP);
  const float2* cb = conf + (size_t)b * A;
  float ce = 0.f;

  if (!ovf){
    for (unsigned int i = t; i < cnt; i += 256){
      ull e = glist[(size_t)b*GCAP + i];
      unsigned int u = (unsigned int)(e >> 32);
      unsigned int sub = (u >> 10) & 2047u;
      if (sub > b2){
        unsigned int a = ~(unsigned int)(e & 0xFFFFFFFFull);
        float2 c = cb[a];
        ce += softplus_(c.y - c.x);
      } else if (sub == b2){
        unsigned int p = atomicAdd(&s_cnt2, 1u);
        if (p < 256u) sb[p] = e;
      }
    }
  } else {
    const ull* mb = negmask + (size_t)b * (A >> 6);
    for (int j = 0; j < (A >> 8); j++){
      int a = (j << 8) + t;
      ull w = mb[a >> 6];
      if ((w >> (a & 63)) & 1ull){
        float2 c = cb[a];
        unsigned int u = xform(c.x);
        if ((u >> 21) == b1){
          unsigned int sub = (u >> 10) & 2047u;
          if (sub > b2){
            ce += softplus_(c.y - c.x);
          } else if (sub == b2){
            unsigned int p = atomicAdd(&s_cnt2, 1u);
            if (p < 256u) sb[p] = ((ull)u << 32) | (unsigned int)(~(unsigned int)a);
          }
        }
      }
    }
  }
  __syncthreads();
  const unsigned int cnt2 = (s_cnt2 < 256u) ? s_cnt2 : 256u;
  for (unsigned int i = t; i < cnt2; i += 256){
    ull ki = sb[i];
    unsigned int rank = 0;
    for (unsigned int j = 0; j < cnt2; j++) rank += (sb[j] > ki) ? 1u : 0u;
    if (rank < R2){
      unsigned int a = ~(unsigned int)(ki & 0xFFFFFFFFull);
      float2 c = cb[a];
      ce += softplus_(c.y - c.x);
    }
  }
#pragma unroll
  for (int s = 32; s >= 1; s >>= 1) ce += __shfl_down(ce, s);
  if (lane == 0) wsum[wid] = ce;
  __syncthreads();
  if (t == 0) atomicAdd(&out[1], (wsum[0]+wsum[1]+wsum[2]+wsum[3]) * cscale);
}

extern "C" void kernel_launch(void* const* d_in, const int* in_sizes, int n_in,
                              void* d_out, int out_size, void* d_ws, size_t ws_size,
                              hipStream_t stream) {
  const float*  loc     = (const float*)d_in[0];
  const float2* conf    = (const float2*)d_in[1];
  const float4* anchors = (const float4*)d_in[2];
  const float*  targets = (const float*)d_in[3];
  int A = in_sizes[2] / 4;
  int B = in_sizes[0] / (A * 4);
  int O = in_sizes[3] / (B * 5);
  int K = 3 * O;
  float* out = (float*)d_out;

  char* wsb = (char*)d_ws;
  size_t off = 0;
  ull* matchbest = (ull*)(wsb + off);              off += (size_t)B * O * sizeof(ull);
  unsigned int* gh1  = (unsigned int*)(wsb + off); off += (size_t)B * 2048 * 4;
  unsigned int* gh2  = (unsigned int*)(wsb + off); off += (size_t)B * 2048 * 4;
  unsigned int* gcnt = (unsigned int*)(wsb + off); off += (size_t)B * 4;
  unsigned int* thr  = (unsigned int*)(wsb + off); off += (size_t)B * 2 * 4;
  size_t zbytes = off;
  off = (off + 7) & ~(size_t)7;
  ull* negmask = (ull*)(wsb + off);                off += (size_t)B * (A >> 6) * sizeof(ull);
  ull* glist   = (ull*)(wsb + off);                off += (size_t)B * GCAP * sizeof(ull);

  hipMemsetAsync(d_ws, 0, zbytes, stream);
  hipMemsetAsync(d_out, 0, 2*sizeof(float), stream);

  float lscale = 1.0f / (float)(B*O);
  float cscale = 1.0f / ((float)(O+K) * (float)(B*O));

  dim3 gA(A/1024, B);
  if (O == 24){
    kA_t<24><<<gA, 256, 0, stream>>>(anchors, targets, conf, matchbest, negmask, gh1, A);
  } else {
    kA_g<<<gA, 256, 0, stream>>>(anchors, targets, matchbest, negmask, A, O);
    dim3 gS(B, A/8192);
    kH1<<<gS, 256, 0, stream>>>(conf, negmask, gh1, A);
  }
  kT1<<<B, 256, 0, stream>>>(gh1, thr, matchbest, loc, targets, conf, out,
                             A, O, K, lscale, cscale);
  dim3 gW(B, A/2048);
  kW<<<gW, 256, 0, stream>>>(conf, negmask, thr, gh2, gcnt, glist, out, A, cscale);
  kF2<<<B, 256, 0, stream>>>(conf, negmask, thr, gh2, gcnt, glist, out, A, cscale);
}